// Round 16
// baseline (290.611 us; speedup 1.0000x reference)
//
#include <hip/hip_runtime.h>
#include <math.h>

#define IN_CH 256
#define HID 64
#define HEADS 8
#define F1 512   // HEADS*HID
#define OUT_CH 16
#define NEG 0.2f
#define NBUCK 16          // CSR source buckets per node (src>>12 -> 13 used)

typedef __attribute__((ext_vector_type(8))) short bf16x8;
typedef __attribute__((ext_vector_type(4))) float f32x4;
typedef __attribute__((ext_vector_type(2))) float f32x2;

__device__ __forceinline__ float bflo(unsigned int v) {
  unsigned int t = v << 16; return __builtin_bit_cast(float, t);
}
__device__ __forceinline__ float bfhi(unsigned int v) {
  unsigned int t = v & 0xFFFF0000u; return __builtin_bit_cast(float, t);
}
__device__ __forceinline__ unsigned short f2bf(float f) {
  unsigned int u = __builtin_bit_cast(unsigned int, f);
  u += 0x7FFFu + ((u >> 16) & 1u);
  return (unsigned short)(u >> 16);
}

// ---------------- prep: bucketed count + W1 reorder-convert + W2 convert ----------------
// CSR key = dst*16 + (src>>12)

__global__ void prep_kernel(const int* __restrict__ ei, int E, int N,
                            int* counts16,
                            const float* __restrict__ W1, unsigned short* __restrict__ W1R,
                            const float* __restrict__ W2, unsigned short* __restrict__ W2T) {
  int idx = blockIdx.x * blockDim.x + threadIdx.x;
  int ET = E + N;
  if (idx < ET) {
    int src, dst;
    if (idx < E) { src = ei[idx]; dst = ei[E + idx]; }
    else         { src = idx - E; dst = idx - E; }
    atomicAdd(&counts16[dst * NBUCK + (src >> 12)], 1);
  }
  if (idx < F1 * IN_CH) {
    int n = idx >> 8, k = idx & 255;
    int r = (((k >> 5) * 4 + ((k >> 3) & 3)) * 512 + n) * 8 + (k & 7);
    W1R[r] = f2bf(W1[k * F1 + n]);
  }
  if (idx < OUT_CH * F1) {
    int n = idx >> 9, k = idx & 511;
    W2T[idx] = f2bf(W2[k * OUT_CH + n]);
  }
}

// scan over n16 = 16N elements, 16 per thread (16384/block); nb must be <= 64
__global__ __launch_bounds__(1024) void scan1_kernel(const int* __restrict__ counts16,
                                                     int* __restrict__ offsets16,
                                                     int* __restrict__ bsum, int n16) {
  __shared__ int lds[1024];
  int t = threadIdx.x;
  int base = blockIdx.x * 16384 + t * 16;
  int v[16];
  int tot = 0;
  if (base < n16) {   // n16 % 16 == 0: all 16 valid when base < n16
    #pragma unroll
    for (int k = 0; k < 4; ++k) {
      int4 c = *(const int4*)(counts16 + base + k * 4);
      v[k * 4 + 0] = c.x; v[k * 4 + 1] = c.y; v[k * 4 + 2] = c.z; v[k * 4 + 3] = c.w;
    }
    #pragma unroll
    for (int k = 0; k < 16; ++k) { int c = v[k]; v[k] = tot; tot += c; }  // v = local excl
  } else {
    #pragma unroll
    for (int k = 0; k < 16; ++k) v[k] = 0;
  }
  lds[t] = tot;
  __syncthreads();
  for (int off = 1; off < 1024; off <<= 1) {
    int u = (t >= off) ? lds[t - off] : 0;
    __syncthreads();
    lds[t] += u;
    __syncthreads();
  }
  int excl = lds[t] - tot;
  if (base < n16) {
    #pragma unroll
    for (int k = 0; k < 4; ++k) {
      int4 o = make_int4(excl + v[k * 4], excl + v[k * 4 + 1],
                         excl + v[k * 4 + 2], excl + v[k * 4 + 3]);
      *(int4*)(offsets16 + base + k * 4) = o;
    }
  }
  if (t == 1023) bsum[blockIdx.x] = lds[1023];
}

__global__ __launch_bounds__(1024) void scan3b_kernel(int* __restrict__ offsets16,
                                                      const int* __restrict__ bsum,
                                                      int nb, int n16) {
  __shared__ int s_pre, s_tot;
  int t = threadIdx.x;
  if (t < 64) {
    int v = (t < nb) ? bsum[t] : 0;
    int vp = (t < (int)blockIdx.x) ? v : 0;
    #pragma unroll
    for (int off = 1; off < 64; off <<= 1) {
      vp += __shfl_xor(vp, off);
      v  += __shfl_xor(v, off);
    }
    if (t == 0) { s_pre = vp; s_tot = v; }
  }
  __syncthreads();
  int base = blockIdx.x * 16384 + t * 16;
  if (base < n16) {
    #pragma unroll
    for (int k = 0; k < 4; ++k) {
      int4 o = *(const int4*)(offsets16 + base + k * 4);
      o.x += s_pre; o.y += s_pre; o.z += s_pre; o.w += s_pre;
      *(int4*)(offsets16 + base + k * 4) = o;
    }
  }
  if (blockIdx.x == 0 && t == 0) offsets16[n16] = s_tot;
}

// fill consumes offsets16 in place: after completion offsets16[k] = orig[k+1].
__global__ void fill_kernel(const int* __restrict__ ei, int E, int N,
                            int* offsets16, int* __restrict__ csr_src) {
  int e = blockIdx.x * blockDim.x + threadIdx.x;
  int ET = E + N;
  if (e >= ET) return;
  int src, dst;
  if (e < E) { src = ei[e]; dst = ei[E + e]; }
  else       { src = e - E; dst = e - E; }
  int key = dst * NBUCK + (src >> 12);
  int pos = atomicAdd(&offsets16[key], 1);
  csr_src[pos] = src;
}

// shifted segment lookup on the consumed offsets array
__device__ __forceinline__ void seg_lookup(const int* __restrict__ offA, int node,
                                           int& beg, int& deg) {
  beg = (node == 0) ? 0 : offA[node * NBUCK - 1];
  deg = offA[node * NBUCK + NBUCK - 1] - beg;
}

// ---------------- GEMM1 v3: barrier-free; B direct from L2-resident W1R ----------------
// h1 stored as fp8 e4m3 (only consumer is aggr1's gather; logits stay fp32).

__global__ __launch_bounds__(512) void gemm1_mfma(const float* __restrict__ X,
                                                  const unsigned short* __restrict__ W1R,
                                                  const float* __restrict__ Asrc,
                                                  const float* __restrict__ Adst,
                                                  unsigned char* __restrict__ C,
                                                  float2* __restrict__ aad1, int M) {
  int tid = threadIdx.x, w = tid >> 6, l = tid & 63;
  int wm = (w >> 2) * 32;
  int wn = (w & 3) * 128;
  int bm = blockIdx.x * 64;
  f32x4 acc[2][8];
  #pragma unroll
  for (int mi = 0; mi < 2; ++mi)
    #pragma unroll
    for (int nj = 0; nj < 8; ++nj) acc[mi][nj] = (f32x4){0.f, 0.f, 0.f, 0.f};
  int kslot = l >> 4;
  for (int kb = 0; kb < 8; ++kb) {
    bf16x8 af[2];
    int kbase = kb * 32 + kslot * 8;
    #pragma unroll
    for (int mi = 0; mi < 2; ++mi) {
      int r = bm + wm + mi * 16 + (l & 15);
      if (r >= M) r = M - 1;
      const float* ap = X + (size_t)r * IN_CH + kbase;
      float4 a0 = *(const float4*)ap;
      float4 a1 = *(const float4*)(ap + 4);
      unsigned int u0, u1, u2, u3;
      asm("v_cvt_pk_bf16_f32 %0, %1, %2" : "=v"(u0) : "v"(a0.x), "v"(a0.y));
      asm("v_cvt_pk_bf16_f32 %0, %1, %2" : "=v"(u1) : "v"(a0.z), "v"(a0.w));
      asm("v_cvt_pk_bf16_f32 %0, %1, %2" : "=v"(u2) : "v"(a1.x), "v"(a1.y));
      asm("v_cvt_pk_bf16_f32 %0, %1, %2" : "=v"(u3) : "v"(a1.z), "v"(a1.w));
      int4 pk = make_int4(u0, u1, u2, u3);
      af[mi] = __builtin_bit_cast(bf16x8, pk);
    }
    const unsigned short* bbase = W1R + (size_t)(kb * 4 + kslot) * 512 * 8;
    #pragma unroll
    for (int nj = 0; nj < 8; ++nj) {
      int n = wn + nj * 16 + (l & 15);
      bf16x8 bf = *(const bf16x8*)(bbase + n * 8);
      acc[0][nj] = __builtin_amdgcn_mfma_f32_16x16x32_bf16(af[0], bf, acc[0][nj], 0, 0, 0);
      acc[1][nj] = __builtin_amdgcn_mfma_f32_16x16x32_bf16(af[1], bf, acc[1][nj], 0, 0, 0);
    }
  }
  float asv[8], adv[8];
  #pragma unroll
  for (int nj = 0; nj < 8; ++nj) {
    int c = wn + nj * 16 + (l & 15);
    asv[nj] = Asrc[c]; adv[nj] = Adst[c];
  }
  int h0 = (w & 3) * 2;
  #pragma unroll
  for (int mi = 0; mi < 2; ++mi) {
    #pragma unroll
    for (int j = 0; j < 4; ++j) {
      int r = bm + wm + mi * 16 + (l >> 4) * 4 + j;
      bool ok = (r < M);
      if (ok) {
        #pragma unroll
        for (int njp = 0; njp < 4; ++njp) {
          int u = __builtin_amdgcn_cvt_pk_fp8_f32(acc[mi][2 * njp][j],
                                                  acc[mi][2 * njp + 1][j], 0, false);
          int c0 = wn + (2 * njp) * 16 + (l & 15);
          C[(size_t)r * F1 + c0]      = (unsigned char)u;
          C[(size_t)r * F1 + c0 + 16] = (unsigned char)(u >> 8);
        }
      }
      float sA = 0.f, dA = 0.f, sB2 = 0.f, dB2 = 0.f;
      #pragma unroll
      for (int nj = 0; nj < 4; ++nj) {
        float v = acc[mi][nj][j];
        sA += v * asv[nj]; dA += v * adv[nj];
      }
      #pragma unroll
      for (int nj = 4; nj < 8; ++nj) {
        float v = acc[mi][nj][j];
        sB2 += v * asv[nj]; dB2 += v * adv[nj];
      }
      #pragma unroll
      for (int off = 1; off < 16; off <<= 1) {
        sA += __shfl_xor(sA, off); dA += __shfl_xor(dA, off);
        sB2 += __shfl_xor(sB2, off); dB2 += __shfl_xor(dB2, off);
      }
      if (ok && (l & 15) == 0) {
        aad1[r * HEADS + h0]     = make_float2(sA, dA);
        aad1[r * HEADS + h0 + 1] = make_float2(sB2, dB2);
      }
    }
  }
}

// ---------------- aggr1: one wave per node, fp8 gather, packed f32x2 accumulate ----------------

__global__ __launch_bounds__(256) void aggr1_kernel(const uint2* __restrict__ h1q,
                                                    const float2* __restrict__ aad1,
                                                    const int* __restrict__ offA,
                                                    const int* __restrict__ csr_src,
                                                    const float* __restrict__ b1,
                                                    uint4* __restrict__ out1v, int N) {
  int tid = threadIdx.x;
  int w = tid >> 6, l = tid & 63;
  // bijective XCD swizzle: each XCD gets a contiguous node-group range
  int b = blockIdx.x;
  int nwg = gridDim.x;
  int q = nwg >> 3, r = nwg & 7;
  int xcd = b & 7, bi = b >> 3;
  int swz = (xcd < r) ? (xcd * (q + 1) + bi) : (r * (q + 1) + (xcd - r) * q + bi);
  int node = swz * 4 + w;
  if (node >= N) return;
  int beg, deg;
  seg_lookup(offA, node, beg, deg);
  int he = l & 7;            // head role in p-compute (lane = e*8 + h)
  int hc = l >> 3;           // head of my channels
  float adv = aad1[node * HEADS + he].y;
  float pden = 0.f;
  f32x2 acc2[4];
  #pragma unroll
  for (int i = 0; i < 4; ++i) acc2[i] = (f32x2){0.f, 0.f};
  int e = l >> 3;
  for (int c0 = 0; c0 < deg; c0 += 8) {
    int cnt = min(8, deg - c0);
    int s8 = 0;
    float p8 = 0.f;
    if (e < cnt) {
      s8 = csr_src[beg + c0 + e];
      float2 sd = aad1[s8 * HEADS + he];
      float ev = sd.x + adv;
      ev = (ev > 0.f) ? ev : NEG * ev;
      p8 = __expf(ev);
      pden += p8;
    }
    if (cnt == 8) {
      int ss[8]; float qq[8];
      #pragma unroll
      for (int j = 0; j < 8; ++j) {
        ss[j] = __shfl(s8, j * 8);
        qq[j] = __shfl(p8, j * 8 + hc);
      }
      uint2 v[8];
      #pragma unroll
      for (int j = 0; j < 8; ++j) v[j] = h1q[(size_t)ss[j] * 64 + l];
      #pragma unroll
      for (int j = 0; j < 8; ++j) {
        f32x2 p2 = (f32x2){qq[j], qq[j]};
        acc2[0] += p2 * __builtin_amdgcn_cvt_pk_f32_fp8(v[j].x, false);
        acc2[1] += p2 * __builtin_amdgcn_cvt_pk_f32_fp8(v[j].x, true);
        acc2[2] += p2 * __builtin_amdgcn_cvt_pk_f32_fp8(v[j].y, false);
        acc2[3] += p2 * __builtin_amdgcn_cvt_pk_f32_fp8(v[j].y, true);
      }
    } else {
      for (int j = 0; j < cnt; ++j) {
        int s = __shfl(s8, j * 8);
        float p = __shfl(p8, j * 8 + hc);
        uint2 v = h1q[(size_t)s * 64 + l];
        f32x2 p2 = (f32x2){p, p};
        acc2[0] += p2 * __builtin_amdgcn_cvt_pk_f32_fp8(v.x, false);
        acc2[1] += p2 * __builtin_amdgcn_cvt_pk_f32_fp8(v.x, true);
        acc2[2] += p2 * __builtin_amdgcn_cvt_pk_f32_fp8(v.y, false);
        acc2[3] += p2 * __builtin_amdgcn_cvt_pk_f32_fp8(v.y, true);
      }
    }
  }
  pden += __shfl_xor(pden, 8);
  pden += __shfl_xor(pden, 16);
  pden += __shfl_xor(pden, 32);
  float den = __shfl(pden, hc) + 1e-16f;
  float4 bv0 = *(const float4*)&b1[l * 8];
  float4 bv1 = *(const float4*)&b1[l * 8 + 4];
  float o[8];
  o[0] = acc2[0][0] / den + bv0.x; o[1] = acc2[0][1] / den + bv0.y;
  o[2] = acc2[1][0] / den + bv0.z; o[3] = acc2[1][1] / den + bv0.w;
  o[4] = acc2[2][0] / den + bv1.x; o[5] = acc2[2][1] / den + bv1.y;
  o[6] = acc2[3][0] / den + bv1.z; o[7] = acc2[3][1] / den + bv1.w;
  #pragma unroll
  for (int i = 0; i < 8; ++i) o[i] = (o[i] > 0.f) ? o[i] : expm1f(o[i]);
  uint4 ov;
  ov.x = (unsigned int)f2bf(o[0]) | ((unsigned int)f2bf(o[1]) << 16);
  ov.y = (unsigned int)f2bf(o[2]) | ((unsigned int)f2bf(o[3]) << 16);
  ov.z = (unsigned int)f2bf(o[4]) | ((unsigned int)f2bf(o[5]) << 16);
  ov.w = (unsigned int)f2bf(o[6]) | ((unsigned int)f2bf(o[7]) << 16);
  out1v[(size_t)node * 64 + l] = ov;
}

// ---------------- GEMM2 v2: barrier-free streaming, A direct from global ----------------

__global__ __launch_bounds__(256) void gemm2_mfma(const unsigned short* __restrict__ A,
                                                  const unsigned short* __restrict__ W2T,
                                                  const float* __restrict__ a_src2,
                                                  const float* __restrict__ a_dst2,
                                                  float* __restrict__ t2,
                                                  float2* __restrict__ aad2, int M) {
  __shared__ __align__(16) short sW[16 * 512];   // 16 KB
  int tid = threadIdx.x, w = tid >> 6, l = tid & 63;
  for (int i = tid; i < 1024; i += 256) ((uint4*)sW)[i] = ((const uint4*)W2T)[i];
  __syncthreads();
  int bm = blockIdx.x * 128 + w * 32;
  f32x4 acc[2];
  acc[0] = (f32x4){0.f, 0.f, 0.f, 0.f};
  acc[1] = (f32x4){0.f, 0.f, 0.f, 0.f};
  int rl = l & 15;
  int koff = (l >> 4) * 8;
  int r0 = bm + rl;       if (r0 >= M) r0 = M - 1;
  int r1 = bm + 16 + rl;  if (r1 >= M) r1 = M - 1;
  const unsigned short* a0p = A + (size_t)r0 * F1 + koff;
  const unsigned short* a1p = A + (size_t)r1 * F1 + koff;
  #pragma unroll
  for (int k0 = 0; k0 < F1; k0 += 32) {
    bf16x8 bfv = *(const bf16x8*)&sW[rl * 512 + k0 + koff];
    bf16x8 af0 = *(const bf16x8*)(a0p + k0);
    bf16x8 af1 = *(const bf16x8*)(a1p + k0);
    acc[0] = __builtin_amdgcn_mfma_f32_16x16x32_bf16(af0, bfv, acc[0], 0, 0, 0);
    acc[1] = __builtin_amdgcn_mfma_f32_16x16x32_bf16(af1, bfv, acc[1], 0, 0, 0);
  }
  float asv = a_src2[rl], adv = a_dst2[rl];
  #pragma unroll
  for (int mi = 0; mi < 2; ++mi) {
    #pragma unroll
    for (int j = 0; j < 4; ++j) {
      int r = bm + mi * 16 + (l >> 4) * 4 + j;
      float val = acc[mi][j];
      float s = val * asv, d = val * adv;
      s += __shfl_xor(s, 1); s += __shfl_xor(s, 2); s += __shfl_xor(s, 4); s += __shfl_xor(s, 8);
      d += __shfl_xor(d, 1); d += __shfl_xor(d, 2); d += __shfl_xor(d, 4); d += __shfl_xor(d, 8);
      if (r < M) {
        t2[(size_t)r * OUT_CH + rl] = val;
        if (rl == 0) aad2[r] = make_float2(s, d);
      }
    }
  }
}

// ---------------- aggr2: 4 nodes/block, 8-deep edge pipeline, log_softmax ----------------

__global__ __launch_bounds__(256) void aggr2_kernel(const float* __restrict__ t2,
                                                    const float2* __restrict__ aad2,
                                                    const int* __restrict__ offA,
                                                    const int* __restrict__ csr_src,
                                                    const float* __restrict__ b2,
                                                    float* __restrict__ out, int N) {
  int tid = threadIdx.x;
  int node = blockIdx.x * 4 + (tid >> 6);
  int lane = tid & 63;
  if (node >= N) return;
  int beg, deg;
  seg_lookup(offA, node, beg, deg);
  float ad = aad2[node].y;
  float acc = 0.f, den = 0.f;
  int eg = lane >> 4, c = lane & 15;
  for (int base = 0; base < deg; base += 8) {
    int j1 = base + eg;
    int j2 = base + 4 + eg;
    bool ok1 = j1 < deg, ok2 = j2 < deg;
    int s1 = csr_src[beg + (ok1 ? j1 : 0)];
    int s2 = csr_src[beg + (ok2 ? j2 : 0)];
    float2 m1 = aad2[s1];
    float2 m2 = aad2[s2];
    float t1v = t2[(size_t)s1 * OUT_CH + c];
    float t2v = t2[(size_t)s2 * OUT_CH + c];
    float e1 = m1.x + ad;
    e1 = (e1 > 0.f) ? e1 : NEG * e1;
    float p1 = ok1 ? __expf(e1) : 0.f;
    float e2 = m2.x + ad;
    e2 = (e2 > 0.f) ? e2 : NEG * e2;
    float p2 = ok2 ? __expf(e2) : 0.f;
    acc += p1 * t1v + p2 * t2v;
    if (c == 0) den += p1 + p2;
  }
  acc += __shfl_xor(acc, 16); acc += __shfl_xor(acc, 32);
  den += __shfl_xor(den, 16); den += __shfl_xor(den, 32);
  den = __shfl(den, 0);
  float val = acc / (den + 1e-16f) + b2[c];
  float mx = val;
  #pragma unroll
  for (int off = 1; off < 16; off <<= 1) mx = fmaxf(mx, __shfl_xor(mx, off));
  float ex = __expf(val - mx);
  float se = ex;
  #pragma unroll
  for (int off = 1; off < 16; off <<= 1) se += __shfl_xor(se, off);
  float ls = val - mx - logf(se);
  if (lane < 16) out[(size_t)node * OUT_CH + lane] = ls;
}

// ---------------- launch ----------------

extern "C" void kernel_launch(void* const* d_in, const int* in_sizes, int n_in,
                              void* d_out, int out_size, void* d_ws, size_t ws_size,
                              hipStream_t stream) {
  const float* x      = (const float*)d_in[0];
  const int*   ei     = (const int*)d_in[1];
  const float* W1     = (const float*)d_in[2];
  const float* a_src1 = (const float*)d_in[3];
  const float* a_dst1 = (const float*)d_in[4];
  const float* b1     = (const float*)d_in[5];
  const float* W2     = (const float*)d_in[6];
  const float* a_src2 = (const float*)d_in[7];
  const float* a_dst2 = (const float*)d_in[8];
  const float* b2     = (const float*)d_in[9];
  float* out = (float*)d_out;

  int N = in_sizes[0] / IN_CH;
  int E = in_sizes[1] / 2;
  int ET = E + N;
  int n16 = N * NBUCK;

  char* w = (char*)d_ws;
  auto alloc = [&](size_t bytes) -> void* {
    void* p = (void*)w;
    w += (bytes + 255) & ~(size_t)255;
    return p;
  };
  unsigned char*  h1b   = (unsigned char*)alloc((size_t)N * F1);       // fp8 e4m3
  unsigned short* out1b = (unsigned short*)alloc((size_t)N * F1 * 2);  // bf16
  unsigned short* w1r   = (unsigned short*)alloc((size_t)F1 * IN_CH * 2);
  unsigned short* w2t   = (unsigned short*)alloc((size_t)OUT_CH * F1 * 2);
  float* aad1  = (float*)alloc((size_t)N * HEADS * 8);
  float* t2    = (float*)alloc((size_t)N * OUT_CH * 4);
  float* aad2  = (float*)alloc((size_t)N * 8);
  int* counts16 = (int*)alloc((size_t)n16 * 4);
  int* offsets16 = (int*)alloc((size_t)(n16 + 1) * 4);
  int* bsum    = (int*)alloc(256 * 4);
  int* csr_src = (int*)alloc((size_t)ET * 4);

  int nb = (n16 + 16383) / 16384;   // 49 for N=50000; must be <= 64

  hipMemsetAsync(counts16, 0, (size_t)n16 * 4, stream);
  prep_kernel<<<(ET + 255) / 256, 256, 0, stream>>>(ei, E, N, counts16, W1, w1r, W2, w2t);
  scan1_kernel<<<nb, 1024, 0, stream>>>(counts16, offsets16, bsum, n16);
  scan3b_kernel<<<nb, 1024, 0, stream>>>(offsets16, bsum, nb, n16);
  fill_kernel<<<(ET + 255) / 256, 256, 0, stream>>>(ei, E, N, offsets16, csr_src);

  gemm1_mfma<<<(N + 63) / 64, 512, 0, stream>>>(x, w1r, a_src1, a_dst1, h1b,
                                                (float2*)aad1, N);
  aggr1_kernel<<<(N + 3) / 4, 256, 0, stream>>>((const uint2*)h1b, (const float2*)aad1,
                                                offsets16, csr_src, b1, (uint4*)out1b, N);
  gemm2_mfma<<<(N + 127) / 128, 256, 0, stream>>>(out1b, w2t, a_src2, a_dst2, t2,
                                                  (float2*)aad2, N);
  aggr2_kernel<<<(N + 3) / 4, 256, 0, stream>>>(t2, (const float2*)aad2, offsets16, csr_src,
                                                b2, out, N);
}

// Round 17
// 264.068 us; speedup vs baseline: 1.1005x; 1.1005x over previous
//
#include <hip/hip_runtime.h>
#include <math.h>

#define IN_CH 256
#define HID 64
#define HEADS 8
#define F1 512   // HEADS*HID
#define OUT_CH 16
#define NEG 0.2f
#define NBUCK 16          // CSR source buckets per node (src>>12 -> 13 used)

typedef __attribute__((ext_vector_type(8))) short bf16x8;
typedef __attribute__((ext_vector_type(4))) float f32x4;
typedef __attribute__((ext_vector_type(2))) float f32x2;

__device__ __forceinline__ unsigned short f2bf(float f) {
  unsigned int u = __builtin_bit_cast(unsigned int, f);
  u += 0x7FFFu + ((u >> 16) & 1u);
  return (unsigned short)(u >> 16);
}
__device__ __forceinline__ void gld_lds16(const void* g, void* l) {
  __builtin_amdgcn_global_load_lds(
      (const __attribute__((address_space(1))) unsigned int*)g,
      (__attribute__((address_space(3))) unsigned int*)l, 16, 0, 0);
}

// ---------------- prep: bucketed count + W1 reorder-convert + W2 convert ----------------
// CSR key = dst*16 + (src>>12)

__global__ void prep_kernel(const int* __restrict__ ei, int E, int N,
                            int* counts16,
                            const float* __restrict__ W1, unsigned short* __restrict__ W1R,
                            const float* __restrict__ W2, unsigned short* __restrict__ W2T) {
  int idx = blockIdx.x * blockDim.x + threadIdx.x;
  int ET = E + N;
  if (idx < ET) {
    int src, dst;
    if (idx < E) { src = ei[idx]; dst = ei[E + idx]; }
    else         { src = idx - E; dst = idx - E; }
    atomicAdd(&counts16[dst * NBUCK + (src >> 12)], 1);
  }
  if (idx < F1 * IN_CH) {
    int n = idx >> 8, k = idx & 255;
    int r = (((k >> 5) * 4 + ((k >> 3) & 3)) * 512 + n) * 8 + (k & 7);
    W1R[r] = f2bf(W1[k * F1 + n]);
  }
  if (idx < OUT_CH * F1) {
    int n = idx >> 9, k = idx & 511;
    W2T[idx] = f2bf(W2[k * OUT_CH + n]);
  }
}

// scan over n16 = 16N elements, 16 per thread (16384/block); nb must be <= 64
__global__ __launch_bounds__(1024) void scan1_kernel(const int* __restrict__ counts16,
                                                     int* __restrict__ offsets16,
                                                     int* __restrict__ bsum, int n16) {
  __shared__ int lds[1024];
  int t = threadIdx.x;
  int base = blockIdx.x * 16384 + t * 16;
  int v[16];
  int tot = 0;
  if (base < n16) {   // n16 % 16 == 0: all 16 valid when base < n16
    #pragma unroll
    for (int k = 0; k < 4; ++k) {
      int4 c = *(const int4*)(counts16 + base + k * 4);
      v[k * 4 + 0] = c.x; v[k * 4 + 1] = c.y; v[k * 4 + 2] = c.z; v[k * 4 + 3] = c.w;
    }
    #pragma unroll
    for (int k = 0; k < 16; ++k) { int c = v[k]; v[k] = tot; tot += c; }  // v = local excl
  } else {
    #pragma unroll
    for (int k = 0; k < 16; ++k) v[k] = 0;
  }
  lds[t] = tot;
  __syncthreads();
  for (int off = 1; off < 1024; off <<= 1) {
    int u = (t >= off) ? lds[t - off] : 0;
    __syncthreads();
    lds[t] += u;
    __syncthreads();
  }
  int excl = lds[t] - tot;
  if (base < n16) {
    #pragma unroll
    for (int k = 0; k < 4; ++k) {
      int4 o = make_int4(excl + v[k * 4], excl + v[k * 4 + 1],
                         excl + v[k * 4 + 2], excl + v[k * 4 + 3]);
      *(int4*)(offsets16 + base + k * 4) = o;
    }
  }
  if (t == 1023) bsum[blockIdx.x] = lds[1023];
}

__global__ __launch_bounds__(1024) void scan3b_kernel(int* __restrict__ offsets16,
                                                      const int* __restrict__ bsum,
                                                      int nb, int n16) {
  __shared__ int s_pre, s_tot;
  int t = threadIdx.x;
  if (t < 64) {
    int v = (t < nb) ? bsum[t] : 0;
    int vp = (t < (int)blockIdx.x) ? v : 0;
    #pragma unroll
    for (int off = 1; off < 64; off <<= 1) {
      vp += __shfl_xor(vp, off);
      v  += __shfl_xor(v, off);
    }
    if (t == 0) { s_pre = vp; s_tot = v; }
  }
  __syncthreads();
  int base = blockIdx.x * 16384 + t * 16;
  if (base < n16) {
    #pragma unroll
    for (int k = 0; k < 4; ++k) {
      int4 o = *(const int4*)(offsets16 + base + k * 4);
      o.x += s_pre; o.y += s_pre; o.z += s_pre; o.w += s_pre;
      *(int4*)(offsets16 + base + k * 4) = o;
    }
  }
  if (blockIdx.x == 0 && t == 0) offsets16[n16] = s_tot;
}

__global__ void fill_kernel(const int* __restrict__ ei, int E, int N,
                            const int* __restrict__ offsets16, int* cursor16,
                            int* __restrict__ csr_src) {
  int e = blockIdx.x * blockDim.x + threadIdx.x;
  int ET = E + N;
  if (e >= ET) return;
  int src, dst;
  if (e < E) { src = ei[e]; dst = ei[E + e]; }
  else       { src = e - E; dst = e - E; }
  int key = dst * NBUCK + (src >> 12);
  int pos = atomicAdd(&cursor16[key], 1);
  csr_src[offsets16[key] + pos] = src;
}

// ---------------- GEMM1 (R14): LDS-staged W1R, BM=64 x BN=512, fused alpha1 ----------------
// h1 stored as fp8 e4m3 (only consumer is aggr1's gather; logits stay fp32).

__global__ __launch_bounds__(512) void gemm1_mfma(const float* __restrict__ X,
                                                  const unsigned short* __restrict__ W1R,
                                                  const float* __restrict__ Asrc,
                                                  const float* __restrict__ Adst,
                                                  unsigned char* __restrict__ C,
                                                  float2* __restrict__ aad1, int M) {
  __shared__ __align__(16) short sB[4 * 512 * 8];  // 32 KB
  int tid = threadIdx.x, w = tid >> 6, l = tid & 63;
  int wm = (w >> 2) * 32;
  int wn = (w & 3) * 128;
  int bm = blockIdx.x * 64;
  f32x4 acc[2][8];
  #pragma unroll
  for (int mi = 0; mi < 2; ++mi)
    #pragma unroll
    for (int nj = 0; nj < 8; ++nj) acc[mi][nj] = (f32x4){0.f, 0.f, 0.f, 0.f};
  int kslot = l >> 4;
  for (int kb = 0; kb < 8; ++kb) {
    __syncthreads();
    const unsigned short* src = W1R + kb * 16384;
    #pragma unroll
    for (int i = 0; i < 4; ++i)
      gld_lds16(src + (size_t)(i * 512 + tid) * 8, (char*)sB + (i * 512 + tid) * 16);
    bf16x8 af[2];
    int kbase = kb * 32 + kslot * 8;
    #pragma unroll
    for (int mi = 0; mi < 2; ++mi) {
      int r = bm + wm + mi * 16 + (l & 15);
      if (r >= M) r = M - 1;
      const float* ap = X + (size_t)r * IN_CH + kbase;
      float4 a0 = *(const float4*)ap;
      float4 a1 = *(const float4*)(ap + 4);
      unsigned int u0, u1, u2, u3;
      asm("v_cvt_pk_bf16_f32 %0, %1, %2" : "=v"(u0) : "v"(a0.x), "v"(a0.y));
      asm("v_cvt_pk_bf16_f32 %0, %1, %2" : "=v"(u1) : "v"(a0.z), "v"(a0.w));
      asm("v_cvt_pk_bf16_f32 %0, %1, %2" : "=v"(u2) : "v"(a1.x), "v"(a1.y));
      asm("v_cvt_pk_bf16_f32 %0, %1, %2" : "=v"(u3) : "v"(a1.z), "v"(a1.w));
      int4 pk = make_int4(u0, u1, u2, u3);
      af[mi] = __builtin_bit_cast(bf16x8, pk);
    }
    __syncthreads();
    #pragma unroll
    for (int nj = 0; nj < 8; ++nj) {
      int n = wn + nj * 16 + (l & 15);
      bf16x8 bf = *(const bf16x8*)&sB[(kslot * 512 + n) * 8];
      acc[0][nj] = __builtin_amdgcn_mfma_f32_16x16x32_bf16(af[0], bf, acc[0][nj], 0, 0, 0);
      acc[1][nj] = __builtin_amdgcn_mfma_f32_16x16x32_bf16(af[1], bf, acc[1][nj], 0, 0, 0);
    }
  }
  float asv[8], adv[8];
  #pragma unroll
  for (int nj = 0; nj < 8; ++nj) {
    int c = wn + nj * 16 + (l & 15);
    asv[nj] = Asrc[c]; adv[nj] = Adst[c];
  }
  int h0 = (w & 3) * 2;
  #pragma unroll
  for (int mi = 0; mi < 2; ++mi) {
    #pragma unroll
    for (int j = 0; j < 4; ++j) {
      int r = bm + wm + mi * 16 + (l >> 4) * 4 + j;
      bool ok = (r < M);
      if (ok) {
        #pragma unroll
        for (int njp = 0; njp < 4; ++njp) {
          int u = __builtin_amdgcn_cvt_pk_fp8_f32(acc[mi][2 * njp][j],
                                                  acc[mi][2 * njp + 1][j], 0, false);
          int c0 = wn + (2 * njp) * 16 + (l & 15);
          C[(size_t)r * F1 + c0]      = (unsigned char)u;
          C[(size_t)r * F1 + c0 + 16] = (unsigned char)(u >> 8);
        }
      }
      float sA = 0.f, dA = 0.f, sB2 = 0.f, dB2 = 0.f;
      #pragma unroll
      for (int nj = 0; nj < 4; ++nj) {
        float v = acc[mi][nj][j];
        sA += v * asv[nj]; dA += v * adv[nj];
      }
      #pragma unroll
      for (int nj = 4; nj < 8; ++nj) {
        float v = acc[mi][nj][j];
        sB2 += v * asv[nj]; dB2 += v * adv[nj];
      }
      #pragma unroll
      for (int off = 1; off < 16; off <<= 1) {
        sA += __shfl_xor(sA, off); dA += __shfl_xor(dA, off);
        sB2 += __shfl_xor(sB2, off); dB2 += __shfl_xor(dB2, off);
      }
      if (ok && (l & 15) == 0) {
        aad1[r * HEADS + h0]     = make_float2(sA, dA);
        aad1[r * HEADS + h0 + 1] = make_float2(sB2, dB2);
      }
    }
  }
}

// ---------------- aggr1: one wave per node, fp8 gather, MLP hoist + packed acc ----------------

__global__ __launch_bounds__(256) void aggr1_kernel(const uint2* __restrict__ h1q,
                                                    const float2* __restrict__ aad1,
                                                    const int* __restrict__ offsets16,
                                                    const int* __restrict__ csr_src,
                                                    const float* __restrict__ b1,
                                                    uint4* __restrict__ out1v, int N) {
  int tid = threadIdx.x;
  int w = tid >> 6, l = tid & 63;
  // bijective XCD swizzle: each XCD gets a contiguous node-group range
  int b = blockIdx.x;
  int nwg = gridDim.x;
  int q = nwg >> 3, r = nwg & 7;
  int xcd = b & 7, bi = b >> 3;
  int swz = (xcd < r) ? (xcd * (q + 1) + bi) : (r * (q + 1) + (xcd - r) * q + bi);
  int node = swz * 4 + w;
  if (node >= N) return;
  int beg = offsets16[node * NBUCK], deg = offsets16[node * NBUCK + NBUCK] - beg;
  int he = l & 7;            // head role in p-compute (lane = e*8 + h)
  int hc = l >> 3;           // head of my channels
  float adv = aad1[node * HEADS + he].y;
  float pden = 0.f;
  f32x2 acc2[4];
  #pragma unroll
  for (int i = 0; i < 4; ++i) acc2[i] = (f32x2){0.f, 0.f};
  int e = l >> 3;
  for (int c0 = 0; c0 < deg; c0 += 8) {
    int cnt = min(8, deg - c0);
    int s8 = 0;
    float p8 = 0.f;
    if (e < cnt) {
      s8 = csr_src[beg + c0 + e];
      float2 sd = aad1[s8 * HEADS + he];
      float ev = sd.x + adv;
      ev = (ev > 0.f) ? ev : NEG * ev;
      p8 = __expf(ev);
      pden += p8;
    }
    if (cnt == 8) {
      int ss[8]; float qq[8];
      #pragma unroll
      for (int j = 0; j < 8; ++j) {
        ss[j] = __shfl(s8, j * 8);
        qq[j] = __shfl(p8, j * 8 + hc);
      }
      uint2 v[8];
      #pragma unroll
      for (int j = 0; j < 8; ++j) v[j] = h1q[(size_t)ss[j] * 64 + l];
      #pragma unroll
      for (int j = 0; j < 8; ++j) {
        f32x2 p2 = (f32x2){qq[j], qq[j]};
        acc2[0] += p2 * __builtin_amdgcn_cvt_pk_f32_fp8(v[j].x, false);
        acc2[1] += p2 * __builtin_amdgcn_cvt_pk_f32_fp8(v[j].x, true);
        acc2[2] += p2 * __builtin_amdgcn_cvt_pk_f32_fp8(v[j].y, false);
        acc2[3] += p2 * __builtin_amdgcn_cvt_pk_f32_fp8(v[j].y, true);
      }
    } else {
      for (int j = 0; j < cnt; ++j) {
        int s = __shfl(s8, j * 8);
        float p = __shfl(p8, j * 8 + hc);
        uint2 v = h1q[(size_t)s * 64 + l];
        f32x2 p2 = (f32x2){p, p};
        acc2[0] += p2 * __builtin_amdgcn_cvt_pk_f32_fp8(v.x, false);
        acc2[1] += p2 * __builtin_amdgcn_cvt_pk_f32_fp8(v.x, true);
        acc2[2] += p2 * __builtin_amdgcn_cvt_pk_f32_fp8(v.y, false);
        acc2[3] += p2 * __builtin_amdgcn_cvt_pk_f32_fp8(v.y, true);
      }
    }
  }
  pden += __shfl_xor(pden, 8);
  pden += __shfl_xor(pden, 16);
  pden += __shfl_xor(pden, 32);
  float den = __shfl(pden, hc) + 1e-16f;
  float4 bv0 = *(const float4*)&b1[l * 8];
  float4 bv1 = *(const float4*)&b1[l * 8 + 4];
  float o[8];
  o[0] = acc2[0][0] / den + bv0.x; o[1] = acc2[0][1] / den + bv0.y;
  o[2] = acc2[1][0] / den + bv0.z; o[3] = acc2[1][1] / den + bv0.w;
  o[4] = acc2[2][0] / den + bv1.x; o[5] = acc2[2][1] / den + bv1.y;
  o[6] = acc2[3][0] / den + bv1.z; o[7] = acc2[3][1] / den + bv1.w;
  #pragma unroll
  for (int i = 0; i < 8; ++i) o[i] = (o[i] > 0.f) ? o[i] : expm1f(o[i]);
  uint4 ov;
  ov.x = (unsigned int)f2bf(o[0]) | ((unsigned int)f2bf(o[1]) << 16);
  ov.y = (unsigned int)f2bf(o[2]) | ((unsigned int)f2bf(o[3]) << 16);
  ov.z = (unsigned int)f2bf(o[4]) | ((unsigned int)f2bf(o[5]) << 16);
  ov.w = (unsigned int)f2bf(o[6]) | ((unsigned int)f2bf(o[7]) << 16);
  out1v[(size_t)node * 64 + l] = ov;
}

// ---------------- GEMM2 v2: barrier-free streaming, A direct from global ----------------

__global__ __launch_bounds__(256) void gemm2_mfma(const unsigned short* __restrict__ A,
                                                  const unsigned short* __restrict__ W2T,
                                                  const float* __restrict__ a_src2,
                                                  const float* __restrict__ a_dst2,
                                                  float* __restrict__ t2,
                                                  float2* __restrict__ aad2, int M) {
  __shared__ __align__(16) short sW[16 * 512];   // 16 KB
  int tid = threadIdx.x, w = tid >> 6, l = tid & 63;
  for (int i = tid; i < 1024; i += 256) ((uint4*)sW)[i] = ((const uint4*)W2T)[i];
  __syncthreads();
  int bm = blockIdx.x * 128 + w * 32;
  f32x4 acc[2];
  acc[0] = (f32x4){0.f, 0.f, 0.f, 0.f};
  acc[1] = (f32x4){0.f, 0.f, 0.f, 0.f};
  int rl = l & 15;
  int koff = (l >> 4) * 8;
  int r0 = bm + rl;       if (r0 >= M) r0 = M - 1;
  int r1 = bm + 16 + rl;  if (r1 >= M) r1 = M - 1;
  const unsigned short* a0p = A + (size_t)r0 * F1 + koff;
  const unsigned short* a1p = A + (size_t)r1 * F1 + koff;
  #pragma unroll
  for (int k0 = 0; k0 < F1; k0 += 32) {
    bf16x8 bfv = *(const bf16x8*)&sW[rl * 512 + k0 + koff];
    bf16x8 af0 = *(const bf16x8*)(a0p + k0);
    bf16x8 af1 = *(const bf16x8*)(a1p + k0);
    acc[0] = __builtin_amdgcn_mfma_f32_16x16x32_bf16(af0, bfv, acc[0], 0, 0, 0);
    acc[1] = __builtin_amdgcn_mfma_f32_16x16x32_bf16(af1, bfv, acc[1], 0, 0, 0);
  }
  float asv = a_src2[rl], adv = a_dst2[rl];
  #pragma unroll
  for (int mi = 0; mi < 2; ++mi) {
    #pragma unroll
    for (int j = 0; j < 4; ++j) {
      int r = bm + mi * 16 + (l >> 4) * 4 + j;
      float val = acc[mi][j];
      float s = val * asv, d = val * adv;
      s += __shfl_xor(s, 1); s += __shfl_xor(s, 2); s += __shfl_xor(s, 4); s += __shfl_xor(s, 8);
      d += __shfl_xor(d, 1); d += __shfl_xor(d, 2); d += __shfl_xor(d, 4); d += __shfl_xor(d, 8);
      if (r < M) {
        t2[(size_t)r * OUT_CH + rl] = val;
        if (rl == 0) aad2[r] = make_float2(s, d);
      }
    }
  }
}

// ---------------- aggr2: 4 nodes/block, 8-deep edge pipeline, log_softmax ----------------

__global__ __launch_bounds__(256) void aggr2_kernel(const float* __restrict__ t2,
                                                    const float2* __restrict__ aad2,
                                                    const int* __restrict__ offsets16,
                                                    const int* __restrict__ csr_src,
                                                    const float* __restrict__ b2,
                                                    float* __restrict__ out, int N) {
  int tid = threadIdx.x;
  int node = blockIdx.x * 4 + (tid >> 6);
  int lane = tid & 63;
  if (node >= N) return;
  int beg = offsets16[node * NBUCK];
  int deg = offsets16[node * NBUCK + NBUCK] - beg;
  float ad = aad2[node].y;
  float acc = 0.f, den = 0.f;
  int eg = lane >> 4, c = lane & 15;
  for (int base = 0; base < deg; base += 8) {
    int j1 = base + eg;
    int j2 = base + 4 + eg;
    bool ok1 = j1 < deg, ok2 = j2 < deg;
    int s1 = csr_src[beg + (ok1 ? j1 : 0)];
    int s2 = csr_src[beg + (ok2 ? j2 : 0)];
    float2 m1 = aad2[s1];
    float2 m2 = aad2[s2];
    float t1v = t2[(size_t)s1 * OUT_CH + c];
    float t2v = t2[(size_t)s2 * OUT_CH + c];
    float e1 = m1.x + ad;
    e1 = (e1 > 0.f) ? e1 : NEG * e1;
    float p1 = ok1 ? __expf(e1) : 0.f;
    float e2 = m2.x + ad;
    e2 = (e2 > 0.f) ? e2 : NEG * e2;
    float p2 = ok2 ? __expf(e2) : 0.f;
    acc += p1 * t1v + p2 * t2v;
    if (c == 0) den += p1 + p2;
  }
  acc += __shfl_xor(acc, 16); acc += __shfl_xor(acc, 32);
  den += __shfl_xor(den, 16); den += __shfl_xor(den, 32);
  den = __shfl(den, 0);
  float val = acc / (den + 1e-16f) + b2[c];
  float mx = val;
  #pragma unroll
  for (int off = 1; off < 16; off <<= 1) mx = fmaxf(mx, __shfl_xor(mx, off));
  float ex = __expf(val - mx);
  float se = ex;
  #pragma unroll
  for (int off = 1; off < 16; off <<= 1) se += __shfl_xor(se, off);
  float ls = val - mx - logf(se);
  if (lane < 16) out[(size_t)node * OUT_CH + lane] = ls;
}

// ---------------- launch ----------------

extern "C" void kernel_launch(void* const* d_in, const int* in_sizes, int n_in,
                              void* d_out, int out_size, void* d_ws, size_t ws_size,
                              hipStream_t stream) {
  const float* x      = (const float*)d_in[0];
  const int*   ei     = (const int*)d_in[1];
  const float* W1     = (const float*)d_in[2];
  const float* a_src1 = (const float*)d_in[3];
  const float* a_dst1 = (const float*)d_in[4];
  const float* b1     = (const float*)d_in[5];
  const float* W2     = (const float*)d_in[6];
  const float* a_src2 = (const float*)d_in[7];
  const float* a_dst2 = (const float*)d_in[8];
  const float* b2     = (const float*)d_in[9];
  float* out = (float*)d_out;

  int N = in_sizes[0] / IN_CH;
  int E = in_sizes[1] / 2;
  int ET = E + N;
  int n16 = N * NBUCK;

  char* w = (char*)d_ws;
  auto alloc = [&](size_t bytes) -> void* {
    void* p = (void*)w;
    w += (bytes + 255) & ~(size_t)255;
    return p;
  };
  unsigned char*  h1b   = (unsigned char*)alloc((size_t)N * F1);       // fp8 e4m3
  unsigned short* out1b = (unsigned short*)alloc((size_t)N * F1 * 2);  // bf16
  unsigned short* w1r   = (unsigned short*)alloc((size_t)F1 * IN_CH * 2);
  unsigned short* w2t   = (unsigned short*)alloc((size_t)OUT_CH * F1 * 2);
  float* aad1  = (float*)alloc((size_t)N * HEADS * 8);
  float* t2    = (float*)alloc((size_t)N * OUT_CH * 4);
  float* aad2  = (float*)alloc((size_t)N * 8);
  int* counts16 = (int*)alloc((size_t)n16 * 2 * 4);   // counts + cursor
  int* cursor16 = counts16 + n16;
  int* offsets16 = (int*)alloc((size_t)(n16 + 1) * 4);
  int* bsum    = (int*)alloc(256 * 4);
  int* csr_src = (int*)alloc((size_t)ET * 4);

  int nb = (n16 + 16383) / 16384;   // 49 for N=50000; must be <= 64

  hipMemsetAsync(counts16, 0, (size_t)n16 * 2 * 4, stream);
  prep_kernel<<<(ET + 255) / 256, 256, 0, stream>>>(ei, E, N, counts16, W1, w1r, W2, w2t);
  scan1_kernel<<<nb, 1024, 0, stream>>>(counts16, offsets16, bsum, n16);
  scan3b_kernel<<<nb, 1024, 0, stream>>>(offsets16, bsum, nb, n16);
  fill_kernel<<<(ET + 255) / 256, 256, 0, stream>>>(ei, E, N, offsets16, cursor16, csr_src);

  gemm1_mfma<<<(N + 63) / 64, 512, 0, stream>>>(x, w1r, a_src1, a_dst1, h1b,
                                                (float2*)aad1, N);
  aggr1_kernel<<<(N + 3) / 4, 256, 0, stream>>>((const uint2*)h1b, (const float2*)aad1,
                                                offsets16, csr_src, b1, (uint4*)out1b, N);
  gemm2_mfma<<<(N + 127) / 128, 256, 0, stream>>>(out1b, w2t, a_src2, a_dst2, t2,
                                                  (float2*)aad2, N);
  aggr2_kernel<<<(N + 3) / 4, 256, 0, stream>>>(t2, (const float2*)aad2, offsets16, csr_src,
                                                b2, out, N);
}

// Round 18
// 259.486 us; speedup vs baseline: 1.1199x; 1.0177x over previous
//
#include <hip/hip_runtime.h>
#include <math.h>

#define IN_CH 256
#define HID 64
#define HEADS 8
#define F1 512   // HEADS*HID
#define OUT_CH 16
#define NEG 0.2f

typedef __attribute__((ext_vector_type(8))) short bf16x8;
typedef __attribute__((ext_vector_type(4))) float f32x4;
typedef __attribute__((ext_vector_type(2))) float f32x2;

__device__ __forceinline__ unsigned short f2bf(float f) {
  unsigned int u = __builtin_bit_cast(unsigned int, f);
  u += 0x7FFFu + ((u >> 16) & 1u);
  return (unsigned short)(u >> 16);
}
__device__ __forceinline__ void gld_lds16(const void* g, void* l) {
  __builtin_amdgcn_global_load_lds(
      (const __attribute__((address_space(1))) unsigned int*)g,
      (__attribute__((address_space(3))) unsigned int*)l, 16, 0, 0);
}

// ---------------- prep: degree count + W1 reorder-convert + W2 convert ----------------

__global__ void prep_kernel(const int* __restrict__ ei, int E, int N,
                            int* counts,
                            const float* __restrict__ W1, unsigned short* __restrict__ W1R,
                            const float* __restrict__ W2, unsigned short* __restrict__ W2T) {
  int idx = blockIdx.x * blockDim.x + threadIdx.x;
  int ET = E + N;
  if (idx < ET) {
    int dst = (idx < E) ? ei[E + idx] : (idx - E);
    atomicAdd(&counts[dst], 1);
  }
  if (idx < F1 * IN_CH) {
    int n = idx >> 8, k = idx & 255;
    int r = (((k >> 5) * 4 + ((k >> 3) & 3)) * 512 + n) * 8 + (k & 7);
    W1R[r] = f2bf(W1[k * F1 + n]);
  }
  if (idx < OUT_CH * F1) {
    int n = idx >> 9, k = idx & 511;
    W2T[idx] = f2bf(W2[k * OUT_CH + n]);
  }
}

// per-block exclusive scan over counts (1 elem/thread); nb must be <= 64
__global__ __launch_bounds__(1024) void scan1_kernel(const int* __restrict__ counts,
                                                     int* __restrict__ offsets,
                                                     int* __restrict__ bsum, int n) {
  __shared__ int lds[1024];
  int t = threadIdx.x;
  int i = blockIdx.x * 1024 + t;
  int v = (i < n) ? counts[i] : 0;
  lds[t] = v;
  __syncthreads();
  for (int off = 1; off < 1024; off <<= 1) {
    int u = (t >= off) ? lds[t - off] : 0;
    __syncthreads();
    lds[t] += u;
    __syncthreads();
  }
  if (i < n) offsets[i] = lds[t] - v;
  if (t == 1023) bsum[blockIdx.x] = lds[1023];
}

// masked wave-sum over bsum (nb <= 64), add block prefix; block0 writes total
__global__ __launch_bounds__(1024) void scan3b_kernel(int* __restrict__ offsets,
                                                      const int* __restrict__ bsum,
                                                      int nb, int n) {
  __shared__ int s_pre, s_tot;
  int t = threadIdx.x;
  if (t < 64) {
    int v = (t < nb) ? bsum[t] : 0;
    int vp = (t < (int)blockIdx.x) ? v : 0;
    #pragma unroll
    for (int off = 1; off < 64; off <<= 1) {
      vp += __shfl_xor(vp, off);
      v  += __shfl_xor(v, off);
    }
    if (t == 0) { s_pre = vp; s_tot = v; }
  }
  __syncthreads();
  int i = blockIdx.x * 1024 + t;
  if (i < n) offsets[i] += s_pre;
  if (blockIdx.x == 0 && t == 0) offsets[n] = s_tot;
}

__global__ void fill_kernel(const int* __restrict__ ei, int E, int N,
                            const int* __restrict__ offsets, int* cursor,
                            int* __restrict__ csr_src) {
  int e = blockIdx.x * blockDim.x + threadIdx.x;
  int ET = E + N;
  if (e >= ET) return;
  int src, dst;
  if (e < E) { src = ei[e]; dst = ei[E + e]; }
  else       { src = e - E; dst = e - E; }
  int pos = atomicAdd(&cursor[dst], 1);
  csr_src[offsets[dst] + pos] = src;
}

// ---------------- GEMM1 (R14): LDS-staged W1R, BM=64 x BN=512, fused alpha1 ----------------
// h1 stored as fp8 e4m3 (only consumer is aggr1's gather; logits stay fp32).

__global__ __launch_bounds__(512) void gemm1_mfma(const float* __restrict__ X,
                                                  const unsigned short* __restrict__ W1R,
                                                  const float* __restrict__ Asrc,
                                                  const float* __restrict__ Adst,
                                                  unsigned char* __restrict__ C,
                                                  float2* __restrict__ aad1, int M) {
  __shared__ __align__(16) short sB[4 * 512 * 8];  // 32 KB
  int tid = threadIdx.x, w = tid >> 6, l = tid & 63;
  int wm = (w >> 2) * 32;
  int wn = (w & 3) * 128;
  int bm = blockIdx.x * 64;
  f32x4 acc[2][8];
  #pragma unroll
  for (int mi = 0; mi < 2; ++mi)
    #pragma unroll
    for (int nj = 0; nj < 8; ++nj) acc[mi][nj] = (f32x4){0.f, 0.f, 0.f, 0.f};
  int kslot = l >> 4;
  for (int kb = 0; kb < 8; ++kb) {
    __syncthreads();
    const unsigned short* src = W1R + kb * 16384;
    #pragma unroll
    for (int i = 0; i < 4; ++i)
      gld_lds16(src + (size_t)(i * 512 + tid) * 8, (char*)sB + (i * 512 + tid) * 16);
    bf16x8 af[2];
    int kbase = kb * 32 + kslot * 8;
    #pragma unroll
    for (int mi = 0; mi < 2; ++mi) {
      int r = bm + wm + mi * 16 + (l & 15);
      if (r >= M) r = M - 1;
      const float* ap = X + (size_t)r * IN_CH + kbase;
      float4 a0 = *(const float4*)ap;
      float4 a1 = *(const float4*)(ap + 4);
      unsigned int u0, u1, u2, u3;
      asm("v_cvt_pk_bf16_f32 %0, %1, %2" : "=v"(u0) : "v"(a0.x), "v"(a0.y));
      asm("v_cvt_pk_bf16_f32 %0, %1, %2" : "=v"(u1) : "v"(a0.z), "v"(a0.w));
      asm("v_cvt_pk_bf16_f32 %0, %1, %2" : "=v"(u2) : "v"(a1.x), "v"(a1.y));
      asm("v_cvt_pk_bf16_f32 %0, %1, %2" : "=v"(u3) : "v"(a1.z), "v"(a1.w));
      int4 pk = make_int4(u0, u1, u2, u3);
      af[mi] = __builtin_bit_cast(bf16x8, pk);
    }
    __syncthreads();
    #pragma unroll
    for (int nj = 0; nj < 8; ++nj) {
      int n = wn + nj * 16 + (l & 15);
      bf16x8 bf = *(const bf16x8*)&sB[(kslot * 512 + n) * 8];
      acc[0][nj] = __builtin_amdgcn_mfma_f32_16x16x32_bf16(af[0], bf, acc[0][nj], 0, 0, 0);
      acc[1][nj] = __builtin_amdgcn_mfma_f32_16x16x32_bf16(af[1], bf, acc[1][nj], 0, 0, 0);
    }
  }
  float asv[8], adv[8];
  #pragma unroll
  for (int nj = 0; nj < 8; ++nj) {
    int c = wn + nj * 16 + (l & 15);
    asv[nj] = Asrc[c]; adv[nj] = Adst[c];
  }
  int h0 = (w & 3) * 2;
  #pragma unroll
  for (int mi = 0; mi < 2; ++mi) {
    #pragma unroll
    for (int j = 0; j < 4; ++j) {
      int r = bm + wm + mi * 16 + (l >> 4) * 4 + j;
      bool ok = (r < M);
      if (ok) {
        #pragma unroll
        for (int njp = 0; njp < 4; ++njp) {
          int u = __builtin_amdgcn_cvt_pk_fp8_f32(acc[mi][2 * njp][j],
                                                  acc[mi][2 * njp + 1][j], 0, false);
          int c0 = wn + (2 * njp) * 16 + (l & 15);
          C[(size_t)r * F1 + c0]      = (unsigned char)u;
          C[(size_t)r * F1 + c0 + 16] = (unsigned char)(u >> 8);
        }
      }
      float sA = 0.f, dA = 0.f, sB2 = 0.f, dB2 = 0.f;
      #pragma unroll
      for (int nj = 0; nj < 4; ++nj) {
        float v = acc[mi][nj][j];
        sA += v * asv[nj]; dA += v * adv[nj];
      }
      #pragma unroll
      for (int nj = 4; nj < 8; ++nj) {
        float v = acc[mi][nj][j];
        sB2 += v * asv[nj]; dB2 += v * adv[nj];
      }
      #pragma unroll
      for (int off = 1; off < 16; off <<= 1) {
        sA += __shfl_xor(sA, off); dA += __shfl_xor(dA, off);
        sB2 += __shfl_xor(sB2, off); dB2 += __shfl_xor(dB2, off);
      }
      if (ok && (l & 15) == 0) {
        aad1[r * HEADS + h0]     = make_float2(sA, dA);
        aad1[r * HEADS + h0 + 1] = make_float2(sB2, dB2);
      }
    }
  }
}

// ---------------- aggr1: one wave per node, fp8 gather, MLP hoist + packed acc ----------------

__global__ __launch_bounds__(256) void aggr1_kernel(const uint2* __restrict__ h1q,
                                                    const float2* __restrict__ aad1,
                                                    const int* __restrict__ offsets,
                                                    const int* __restrict__ csr_src,
                                                    const float* __restrict__ b1,
                                                    uint4* __restrict__ out1v, int N) {
  int tid = threadIdx.x;
  int w = tid >> 6, l = tid & 63;
  // bijective XCD swizzle: each XCD gets a contiguous node-group range
  int b = blockIdx.x;
  int nwg = gridDim.x;
  int q = nwg >> 3, r = nwg & 7;
  int xcd = b & 7, bi = b >> 3;
  int swz = (xcd < r) ? (xcd * (q + 1) + bi) : (r * (q + 1) + (xcd - r) * q + bi);
  int node = swz * 4 + w;
  if (node >= N) return;
  int beg = offsets[node], deg = offsets[node + 1] - beg;
  int he = l & 7;            // head role in p-compute (lane = e*8 + h)
  int hc = l >> 3;           // head of my channels
  float adv = aad1[node * HEADS + he].y;
  float pden = 0.f;
  f32x2 acc2[4];
  #pragma unroll
  for (int i = 0; i < 4; ++i) acc2[i] = (f32x2){0.f, 0.f};
  int e = l >> 3;
  for (int c0 = 0; c0 < deg; c0 += 8) {
    int cnt = min(8, deg - c0);
    int s8 = 0;
    float p8 = 0.f;
    if (e < cnt) {
      s8 = csr_src[beg + c0 + e];
      float2 sd = aad1[s8 * HEADS + he];
      float ev = sd.x + adv;
      ev = (ev > 0.f) ? ev : NEG * ev;
      p8 = __expf(ev);
      pden += p8;
    }
    if (cnt == 8) {
      int ss[8]; float qq[8];
      #pragma unroll
      for (int j = 0; j < 8; ++j) {
        ss[j] = __shfl(s8, j * 8);
        qq[j] = __shfl(p8, j * 8 + hc);
      }
      uint2 v[8];
      #pragma unroll
      for (int j = 0; j < 8; ++j) v[j] = h1q[(size_t)ss[j] * 64 + l];
      #pragma unroll
      for (int j = 0; j < 8; ++j) {
        f32x2 p2 = (f32x2){qq[j], qq[j]};
        acc2[0] += p2 * __builtin_amdgcn_cvt_pk_f32_fp8(v[j].x, false);
        acc2[1] += p2 * __builtin_amdgcn_cvt_pk_f32_fp8(v[j].x, true);
        acc2[2] += p2 * __builtin_amdgcn_cvt_pk_f32_fp8(v[j].y, false);
        acc2[3] += p2 * __builtin_amdgcn_cvt_pk_f32_fp8(v[j].y, true);
      }
    } else {
      for (int j = 0; j < cnt; ++j) {
        int s = __shfl(s8, j * 8);
        float p = __shfl(p8, j * 8 + hc);
        uint2 v = h1q[(size_t)s * 64 + l];
        f32x2 p2 = (f32x2){p, p};
        acc2[0] += p2 * __builtin_amdgcn_cvt_pk_f32_fp8(v.x, false);
        acc2[1] += p2 * __builtin_amdgcn_cvt_pk_f32_fp8(v.x, true);
        acc2[2] += p2 * __builtin_amdgcn_cvt_pk_f32_fp8(v.y, false);
        acc2[3] += p2 * __builtin_amdgcn_cvt_pk_f32_fp8(v.y, true);
      }
    }
  }
  pden += __shfl_xor(pden, 8);
  pden += __shfl_xor(pden, 16);
  pden += __shfl_xor(pden, 32);
  float den = __shfl(pden, hc) + 1e-16f;
  float4 bv0 = *(const float4*)&b1[l * 8];
  float4 bv1 = *(const float4*)&b1[l * 8 + 4];
  float o[8];
  o[0] = acc2[0][0] / den + bv0.x; o[1] = acc2[0][1] / den + bv0.y;
  o[2] = acc2[1][0] / den + bv0.z; o[3] = acc2[1][1] / den + bv0.w;
  o[4] = acc2[2][0] / den + bv1.x; o[5] = acc2[2][1] / den + bv1.y;
  o[6] = acc2[3][0] / den + bv1.z; o[7] = acc2[3][1] / den + bv1.w;
  #pragma unroll
  for (int i = 0; i < 8; ++i) o[i] = (o[i] > 0.f) ? o[i] : expm1f(o[i]);
  uint4 ov;
  ov.x = (unsigned int)f2bf(o[0]) | ((unsigned int)f2bf(o[1]) << 16);
  ov.y = (unsigned int)f2bf(o[2]) | ((unsigned int)f2bf(o[3]) << 16);
  ov.z = (unsigned int)f2bf(o[4]) | ((unsigned int)f2bf(o[5]) << 16);
  ov.w = (unsigned int)f2bf(o[6]) | ((unsigned int)f2bf(o[7]) << 16);
  out1v[(size_t)node * 64 + l] = ov;
}

// ---------------- GEMM2 v2: barrier-free streaming, A direct from global ----------------

__global__ __launch_bounds__(256) void gemm2_mfma(const unsigned short* __restrict__ A,
                                                  const unsigned short* __restrict__ W2T,
                                                  const float* __restrict__ a_src2,
                                                  const float* __restrict__ a_dst2,
                                                  float* __restrict__ t2,
                                                  float2* __restrict__ aad2, int M) {
  __shared__ __align__(16) short sW[16 * 512];   // 16 KB
  int tid = threadIdx.x, w = tid >> 6, l = tid & 63;
  for (int i = tid; i < 1024; i += 256) ((uint4*)sW)[i] = ((const uint4*)W2T)[i];
  __syncthreads();
  int bm = blockIdx.x * 128 + w * 32;
  f32x4 acc[2];
  acc[0] = (f32x4){0.f, 0.f, 0.f, 0.f};
  acc[1] = (f32x4){0.f, 0.f, 0.f, 0.f};
  int rl = l & 15;
  int koff = (l >> 4) * 8;
  int r0 = bm + rl;       if (r0 >= M) r0 = M - 1;
  int r1 = bm + 16 + rl;  if (r1 >= M) r1 = M - 1;
  const unsigned short* a0p = A + (size_t)r0 * F1 + koff;
  const unsigned short* a1p = A + (size_t)r1 * F1 + koff;
  #pragma unroll
  for (int k0 = 0; k0 < F1; k0 += 32) {
    bf16x8 bfv = *(const bf16x8*)&sW[rl * 512 + k0 + koff];
    bf16x8 af0 = *(const bf16x8*)(a0p + k0);
    bf16x8 af1 = *(const bf16x8*)(a1p + k0);
    acc[0] = __builtin_amdgcn_mfma_f32_16x16x32_bf16(af0, bfv, acc[0], 0, 0, 0);
    acc[1] = __builtin_amdgcn_mfma_f32_16x16x32_bf16(af1, bfv, acc[1], 0, 0, 0);
  }
  float asv = a_src2[rl], adv = a_dst2[rl];
  #pragma unroll
  for (int mi = 0; mi < 2; ++mi) {
    #pragma unroll
    for (int j = 0; j < 4; ++j) {
      int r = bm + mi * 16 + (l >> 4) * 4 + j;
      float val = acc[mi][j];
      float s = val * asv, d = val * adv;
      s += __shfl_xor(s, 1); s += __shfl_xor(s, 2); s += __shfl_xor(s, 4); s += __shfl_xor(s, 8);
      d += __shfl_xor(d, 1); d += __shfl_xor(d, 2); d += __shfl_xor(d, 4); d += __shfl_xor(d, 8);
      if (r < M) {
        t2[(size_t)r * OUT_CH + rl] = val;
        if (rl == 0) aad2[r] = make_float2(s, d);
      }
    }
  }
}

// ---------------- aggr2: 4 nodes/block, 8-deep edge pipeline, log_softmax ----------------

__global__ __launch_bounds__(256) void aggr2_kernel(const float* __restrict__ t2,
                                                    const float2* __restrict__ aad2,
                                                    const int* __restrict__ offsets,
                                                    const int* __restrict__ csr_src,
                                                    const float* __restrict__ b2,
                                                    float* __restrict__ out, int N) {
  int tid = threadIdx.x;
  int node = blockIdx.x * 4 + (tid >> 6);
  int lane = tid & 63;
  if (node >= N) return;
  int beg = offsets[node];
  int deg = offsets[node + 1] - beg;
  float ad = aad2[node].y;
  float acc = 0.f, den = 0.f;
  int eg = lane >> 4, c = lane & 15;
  for (int base = 0; base < deg; base += 8) {
    int j1 = base + eg;
    int j2 = base + 4 + eg;
    bool ok1 = j1 < deg, ok2 = j2 < deg;
    int s1 = csr_src[beg + (ok1 ? j1 : 0)];
    int s2 = csr_src[beg + (ok2 ? j2 : 0)];
    float2 m1 = aad2[s1];
    float2 m2 = aad2[s2];
    float t1v = t2[(size_t)s1 * OUT_CH + c];
    float t2v = t2[(size_t)s2 * OUT_CH + c];
    float e1 = m1.x + ad;
    e1 = (e1 > 0.f) ? e1 : NEG * e1;
    float p1 = ok1 ? __expf(e1) : 0.f;
    float e2 = m2.x + ad;
    e2 = (e2 > 0.f) ? e2 : NEG * e2;
    float p2 = ok2 ? __expf(e2) : 0.f;
    acc += p1 * t1v + p2 * t2v;
    if (c == 0) den += p1 + p2;
  }
  acc += __shfl_xor(acc, 16); acc += __shfl_xor(acc, 32);
  den += __shfl_xor(den, 16); den += __shfl_xor(den, 32);
  den = __shfl(den, 0);
  float val = acc / (den + 1e-16f) + b2[c];
  float mx = val;
  #pragma unroll
  for (int off = 1; off < 16; off <<= 1) mx = fmaxf(mx, __shfl_xor(mx, off));
  float ex = __expf(val - mx);
  float se = ex;
  #pragma unroll
  for (int off = 1; off < 16; off <<= 1) se += __shfl_xor(se, off);
  float ls = val - mx - logf(se);
  if (lane < 16) out[(size_t)node * OUT_CH + lane] = ls;
}

// ---------------- launch ----------------

extern "C" void kernel_launch(void* const* d_in, const int* in_sizes, int n_in,
                              void* d_out, int out_size, void* d_ws, size_t ws_size,
                              hipStream_t stream) {
  const float* x      = (const float*)d_in[0];
  const int*   ei     = (const int*)d_in[1];
  const float* W1     = (const float*)d_in[2];
  const float* a_src1 = (const float*)d_in[3];
  const float* a_dst1 = (const float*)d_in[4];
  const float* b1     = (const float*)d_in[5];
  const float* W2     = (const float*)d_in[6];
  const float* a_src2 = (const float*)d_in[7];
  const float* a_dst2 = (const float*)d_in[8];
  const float* b2     = (const float*)d_in[9];
  float* out = (float*)d_out;

  int N = in_sizes[0] / IN_CH;
  int E = in_sizes[1] / 2;
  int ET = E + N;

  char* w = (char*)d_ws;
  auto alloc = [&](size_t bytes) -> void* {
    void* p = (void*)w;
    w += (bytes + 255) & ~(size_t)255;
    return p;
  };
  unsigned char*  h1b   = (unsigned char*)alloc((size_t)N * F1);       // fp8 e4m3
  unsigned short* out1b = (unsigned short*)alloc((size_t)N * F1 * 2);  // bf16
  unsigned short* w1r   = (unsigned short*)alloc((size_t)F1 * IN_CH * 2);
  unsigned short* w2t   = (unsigned short*)alloc((size_t)OUT_CH * F1 * 2);
  float* aad1  = (float*)alloc((size_t)N * HEADS * 8);
  float* t2    = (float*)alloc((size_t)N * OUT_CH * 4);
  float* aad2  = (float*)alloc((size_t)N * 8);
  int* counts  = (int*)alloc((size_t)N * 2 * 4);   // counts + cursor
  int* cursor  = counts + N;
  int* offsets = (int*)alloc((size_t)(N + 1) * 4);
  int* bsum    = (int*)alloc(256 * 4);
  int* csr_src = (int*)alloc((size_t)ET * 4);

  int nb = (N + 1023) / 1024;   // 49 for N=50000; must be <= 64

  hipMemsetAsync(counts, 0, (size_t)N * 2 * 4, stream);
  prep_kernel<<<(ET + 255) / 256, 256, 0, stream>>>(ei, E, N, counts, W1, w1r, W2, w2t);
  scan1_kernel<<<nb, 1024, 0, stream>>>(counts, offsets, bsum, N);
  scan3b_kernel<<<nb, 1024, 0, stream>>>(offsets, bsum, nb, N);
  fill_kernel<<<(ET + 255) / 256, 256, 0, stream>>>(ei, E, N, offsets, cursor, csr_src);

  gemm1_mfma<<<(N + 63) / 64, 512, 0, stream>>>(x, w1r, a_src1, a_dst1, h1b,
                                                (float2*)aad1, N);
  aggr1_kernel<<<(N + 3) / 4, 256, 0, stream>>>((const uint2*)h1b, (const float2*)aad1,
                                                offsets, csr_src, b1, (uint4*)out1b, N);
  gemm2_mfma<<<(N + 127) / 128, 256, 0, stream>>>(out1b, w2t, a_src2, a_dst2, t2,
                                                  (float2*)aad2, N);
  aggr2_kernel<<<(N + 3) / 4, 256, 0, stream>>>(t2, (const float2*)aad2, offsets, csr_src,
                                                b2, out, N);
}